// Round 1
// baseline (95.930 us; speedup 1.0000x reference)
//
#include <hip/hip_runtime.h>

// n-step return: T=1024, B=4096, gamma=0.99, horizon=16, fp32 in/out.
// G[t,b] = sum_{h=0}^{15} g^h * rm[t+h,b]  (rm = rewards*masks, zero-padded past T)
//        + g^{min(t+16,T)-t} * values[min(t+15,T-1), b]
//
// R3: float4 vectorization (16B/lane — coalescing sweet spot), CT=8.
// Theory: R2 (scalar, CT=16, 89.8us) ran at ~17% of achievable BW with trivial
// VALU -> VMEM-issue/latency-bound on 4B/lane loads (256B/wave-inst).
// float4 gives 1KB/wave-inst, 54 loads/thread (vs 78), 8 stores (vs 16).
// Grid: 128 time-chunks x 1024 float4-cols = 131072 threads = 2048 waves
// = 8 waves/CU (2/SIMD at the <=256-VGPR band) — full single-generation
// residency. Halo re-reads (23/8 = 2.9x on r,m) are L3-resident (48MB < 256MB).

constexpr int   T_DIM  = 1024;
constexpr int   B_DIM  = 4096;
constexpr int   B4     = B_DIM / 4;   // 1024 float4 columns
constexpr int   H      = 16;          // horizon
constexpr int   CT     = 8;           // timesteps per thread
constexpr int   HALO   = H - 1;       // 15
constexpr int   ROWS   = CT + HALO;   // 23 staged rm rows
constexpr float GAMMA  = 0.99f;

constexpr float gpow_c(int n) {
    float g = 1.0f;
    for (int i = 0; i < n; ++i) g *= GAMMA;
    return g;
}
constexpr float G16 = gpow_c(16);

__device__ __forceinline__ float4 f4_mul(float4 a, float4 b) {
    return make_float4(a.x * b.x, a.y * b.y, a.z * b.z, a.w * b.w);
}
// s*a + b, componentwise
__device__ __forceinline__ float4 f4_fma(float s, float4 a, float4 b) {
    return make_float4(fmaf(s, a.x, b.x), fmaf(s, a.y, b.y),
                       fmaf(s, a.z, b.z), fmaf(s, a.w, b.w));
}

__global__ __launch_bounds__(256, 2)
void NStepReturn_88691074662796_kernel(const float4* __restrict__ rewards,
                                       const float4* __restrict__ values,
                                       const float4* __restrict__ masks,
                                       float4* __restrict__ out)
{
    const int b4 = blockIdx.x * 256 + threadIdx.x;        // float4 column
    const int t0 = blockIdx.y * CT;                       // chunk start

    // ---- stage rm = rewards*masks for all needed rows (max loads in flight) ----
    float4 rm[ROWS];
    #pragma unroll
    for (int i = 0; i < ROWS; ++i) {
        const int t = t0 + i;                             // may exceed T-1 in last chunks
        if (t < T_DIM) {
            const float4 r = rewards[t * B4 + b4];
            const float4 m = masks[t * B4 + b4];
            rm[i] = f4_mul(r, m);
        } else {
            rm[i] = make_float4(0.0f, 0.0f, 0.0f, 0.0f);
        }
    }
    float4 v[CT];
    #pragma unroll
    for (int i = 0; i < CT; ++i) {
        const int vi = min(t0 + i + H - 1, T_DIM - 1);
        v[i] = values[vi * B4 + b4];
    }

    // ---- init: W(t_last) = sum_{h=0}^{15} g^h rm[t_last+h] (Horner) ----
    float4 W = make_float4(0.0f, 0.0f, 0.0f, 0.0f);
    #pragma unroll
    for (int h = H - 1; h >= 0; --h) W = f4_fma(GAMMA, W, rm[CT - 1 + h]);

    {   // bootstrap for t_last
        const int t = t0 + CT - 1;
        float gb = G16;
        if (t + H > T_DIM) {                              // uniform; last chunks only
            gb = 1.0f;
            for (int k = 0; k < T_DIM - t; ++k) gb *= GAMMA;
        }
        out[t * B4 + b4] = f4_fma(gb, v[CT - 1], W);
    }

    // ---- backward sweep: W(t) = rm[t] + g*W(t+1) - g^16*rm[t+16] ----
    #pragma unroll
    for (int j = CT - 2; j >= 0; --j) {
        const int t = t0 + j;
        W = f4_fma(GAMMA, W, rm[j]);                      // rm[t] + g*W
        W = f4_fma(-G16, rm[j + H], W);                   // - g^16 * rm[t+16]

        float gb = G16;
        if (t + H > T_DIM) {                              // uniform; last chunks only
            gb = 1.0f;
            for (int k = 0; k < T_DIM - t; ++k) gb *= GAMMA;
        }
        out[t * B4 + b4] = f4_fma(gb, v[j], W);
    }
}

extern "C" void kernel_launch(void* const* d_in, const int* in_sizes, int n_in,
                              void* d_out, int out_size, void* d_ws, size_t ws_size,
                              hipStream_t stream) {
    const float4* rewards = (const float4*)d_in[0];
    const float4* values  = (const float4*)d_in[1];
    const float4* masks   = (const float4*)d_in[2];
    float4* out = (float4*)d_out;

    dim3 grid(B4 / 256, T_DIM / CT);   // (4, 128) = 512 blocks, 4 waves each
    dim3 block(256);
    NStepReturn_88691074662796_kernel<<<grid, block, 0, stream>>>(rewards, values, masks, out);
}